// Round 6
// baseline (975.838 us; speedup 1.0000x reference)
//
#include <hip/hip_runtime.h>
#include <hip/hip_bf16.h>

#define Bz 16
#define Nn 512
#define Dd 512
#define Hh 8
#define HD 64

static const long NNl  = (long)Nn * Nn;        // 262144
static const long BNNl = (long)Bz * Nn * Nn;   // 4194304

__device__ inline float bf2f(unsigned short u) {
    unsigned int x = ((unsigned int)u) << 16;
    return __uint_as_float(x);
}
__device__ inline unsigned short f2bf(float f) {
    __hip_bfloat16 h = __float2bfloat16(f);
    return *reinterpret_cast<unsigned short*>(&h);
}

// ---------------------------------------------------------------------------
// Kernel 1: P = row-normalized masked adjacency. One wave per (b, row).
// ---------------------------------------------------------------------------
__global__ __launch_bounds__(64)
void computeP(const float* __restrict__ adj, const int* __restrict__ mask,
              float* __restrict__ P)
{
    const int i = blockIdx.x;
    const int b = blockIdx.y;
    const int lane = threadIdx.x;
    const float* arow = adj + ((long)b * Nn + i) * Nn;
    const int*   mrow = mask + (long)b * Nn;
    const bool mi = (mrow[i] != 0);

    float vals[8];
    float s = 0.f;
    #pragma unroll
    for (int t = 0; t < 2; ++t) {
        const int c = lane * 4 + t * 256;
        float4 a4 = *(const float4*)&arow[c];
        int4   m4 = *(const int4*)&mrow[c];
        float v0 = (mi && m4.x) ? a4.x : 0.f;
        float v1 = (mi && m4.y) ? a4.y : 0.f;
        float v2 = (mi && m4.z) ? a4.z : 0.f;
        float v3 = (mi && m4.w) ? a4.w : 0.f;
        vals[t*4+0] = v0; vals[t*4+1] = v1; vals[t*4+2] = v2; vals[t*4+3] = v3;
        s += v0 + v1 + v2 + v3;
    }
    #pragma unroll
    for (int o = 1; o < 64; o <<= 1) s += __shfl_xor(s, o);
    const float den = (s == 0.f) ? 1.f : s;

    float* prow = P + ((long)b * Nn + i) * Nn;
    #pragma unroll
    for (int t = 0; t < 2; ++t) {
        const int c = lane * 4 + t * 256;
        float4 o4;
        o4.x = vals[t*4+0] / den;
        o4.y = vals[t*4+1] / den;
        o4.z = vals[t*4+2] / den;
        o4.w = vals[t*4+3] / den;
        *(float4*)&prow[c] = o4;
    }
}

// ---------------------------------------------------------------------------
// Kernel 2a: batched fp32 GEMM, 128x128 tile (qkv projection).
// ---------------------------------------------------------------------------
template<bool BT, bool BIAS>
__global__ __launch_bounds__(256)
void gemm128(const float* __restrict__ A, const float* __restrict__ Bm,
             const float* __restrict__ bias, float* __restrict__ C,
             int M, int N, int K, long sA, long sB, long sC)
{
    __shared__ float As[16][128];
    __shared__ float Bs[16][128];

    const int bz = blockIdx.z;
    A  += (long)bz * sA;
    Bm += (long)bz * sB;
    C  += (long)bz * sC;
    const int bm = blockIdx.y * 128;
    const int bn = blockIdx.x * 128;
    const int tid = threadIdx.x;
    const int tx = tid & 15;
    const int ty = tid >> 4;

    float acc[8][8];
    #pragma unroll
    for (int i = 0; i < 8; ++i)
        #pragma unroll
        for (int j = 0; j < 8; ++j) acc[i][j] = 0.f;

    for (int k0 = 0; k0 < K; k0 += 16) {
        #pragma unroll
        for (int i = 0; i < 2; ++i) {
            const int r = (tid >> 2) + i * 64;
            const int c = (tid & 3) * 4;
            float4 a4 = *(const float4*)&A[(long)(bm + r) * K + k0 + c];
            As[c+0][r] = a4.x; As[c+1][r] = a4.y;
            As[c+2][r] = a4.z; As[c+3][r] = a4.w;
        }
        if (!BT) {
            #pragma unroll
            for (int i = 0; i < 2; ++i) {
                const int kk = (tid >> 5) + i * 8;
                const int c  = (tid & 31) * 4;
                *(float4*)&Bs[kk][c] =
                    *(const float4*)&Bm[(long)(k0 + kk) * N + bn + c];
            }
        } else {
            #pragma unroll
            for (int i = 0; i < 2; ++i) {
                const int cc = (tid >> 2) + i * 64;
                const int kk = (tid & 3) * 4;
                float4 b4 = *(const float4*)&Bm[(long)(bn + cc) * K + k0 + kk];
                Bs[kk+0][cc] = b4.x; Bs[kk+1][cc] = b4.y;
                Bs[kk+2][cc] = b4.z; Bs[kk+3][cc] = b4.w;
            }
        }
        __syncthreads();

        #pragma unroll
        for (int kk = 0; kk < 16; ++kk) {
            float a[8], bb[8];
            *(float4*)&a[0]  = *(const float4*)&As[kk][ty*4];
            *(float4*)&a[4]  = *(const float4*)&As[kk][64 + ty*4];
            *(float4*)&bb[0] = *(const float4*)&Bs[kk][tx*4];
            *(float4*)&bb[4] = *(const float4*)&Bs[kk][64 + tx*4];
            #pragma unroll
            for (int i = 0; i < 8; ++i)
                #pragma unroll
                for (int j = 0; j < 8; ++j)
                    acc[i][j] = fmaf(a[i], bb[j], acc[i][j]);
        }
        __syncthreads();
    }

    float bv[8];
    if (BIAS) {
        *(float4*)&bv[0] = *(const float4*)&bias[bn + tx*4];
        *(float4*)&bv[4] = *(const float4*)&bias[bn + 64 + tx*4];
    }
    #pragma unroll
    for (int i = 0; i < 8; ++i) {
        const int r = bm + ((i < 4) ? (ty*4 + i) : (64 + ty*4 + (i - 4)));
        float o0[4], o1[4];
        #pragma unroll
        for (int j = 0; j < 4; ++j) {
            o0[j] = acc[i][j]     + (BIAS ? bv[j]     : 0.f);
            o1[j] = acc[i][j + 4] + (BIAS ? bv[j + 4] : 0.f);
        }
        *(float4*)&C[(long)r * N + bn + tx*4]      = *(float4*)o0;
        *(float4*)&C[(long)r * N + bn + 64 + tx*4] = *(float4*)o1;
    }
}

// ---------------------------------------------------------------------------
// Kernel 2b: 128x64-tile GEMM (powers + out-proj; 512 blocks = 2/CU).
// ---------------------------------------------------------------------------
template<bool BT, bool BIAS>
__global__ __launch_bounds__(256)
void gemm64(const float* __restrict__ A, const float* __restrict__ Bm,
            const float* __restrict__ bias, float* __restrict__ C,
            int M, int N, int K, long sA, long sB, long sC)
{
    __shared__ float As[16][128];
    __shared__ float Bs[16][64];

    const int bz = blockIdx.z;
    A  += (long)bz * sA;
    Bm += (long)bz * sB;
    C  += (long)bz * sC;
    const int bm = blockIdx.y * 128;
    const int bn = blockIdx.x * 64;
    const int tid = threadIdx.x;
    const int tx = tid & 15;
    const int ty = tid >> 4;

    float acc[8][4];
    #pragma unroll
    for (int i = 0; i < 8; ++i)
        #pragma unroll
        for (int j = 0; j < 4; ++j) acc[i][j] = 0.f;

    for (int k0 = 0; k0 < K; k0 += 16) {
        #pragma unroll
        for (int i = 0; i < 2; ++i) {
            const int r = (tid >> 2) + i * 64;
            const int c = (tid & 3) * 4;
            float4 a4 = *(const float4*)&A[(long)(bm + r) * K + k0 + c];
            As[c+0][r] = a4.x; As[c+1][r] = a4.y;
            As[c+2][r] = a4.z; As[c+3][r] = a4.w;
        }
        if (!BT) {
            const int kk = tid >> 4;
            const int c  = (tid & 15) * 4;
            *(float4*)&Bs[kk][c] =
                *(const float4*)&Bm[(long)(k0 + kk) * N + bn + c];
        } else {
            const int cc = tid >> 2;
            const int kk = (tid & 3) * 4;
            float4 b4 = *(const float4*)&Bm[(long)(bn + cc) * K + k0 + kk];
            Bs[kk+0][cc] = b4.x; Bs[kk+1][cc] = b4.y;
            Bs[kk+2][cc] = b4.z; Bs[kk+3][cc] = b4.w;
        }
        __syncthreads();

        #pragma unroll
        for (int kk = 0; kk < 16; ++kk) {
            float a[8], bb[4];
            *(float4*)&a[0]  = *(const float4*)&As[kk][ty*4];
            *(float4*)&a[4]  = *(const float4*)&As[kk][64 + ty*4];
            *(float4*)&bb[0] = *(const float4*)&Bs[kk][tx*4];
            #pragma unroll
            for (int i = 0; i < 8; ++i)
                #pragma unroll
                for (int j = 0; j < 4; ++j)
                    acc[i][j] = fmaf(a[i], bb[j], acc[i][j]);
        }
        __syncthreads();
    }

    float bv[4];
    if (BIAS) *(float4*)&bv[0] = *(const float4*)&bias[bn + tx*4];
    #pragma unroll
    for (int i = 0; i < 8; ++i) {
        const int r = bm + ((i < 4) ? (ty*4 + i) : (64 + ty*4 + (i - 4)));
        float o0[4];
        #pragma unroll
        for (int j = 0; j < 4; ++j)
            o0[j] = acc[i][j] + (BIAS ? bv[j] : 0.f);
        *(float4*)&C[(long)r * N + bn + tx*4] = *(float4*)o0;
    }
}

// ---------------------------------------------------------------------------
// Kernel 3: precompute edge-FFN bias -> [B][H][N][N] (fp32 or bf16).
// ---------------------------------------------------------------------------
template<bool BF16OUT>
__global__ __launch_bounds__(256)
void bias_ffn(const float* __restrict__ powers,
              const float* __restrict__ w1, const float* __restrict__ b1,
              const float* __restrict__ w2, const float* __restrict__ b2,
              void* __restrict__ biasOut)
{
    __shared__ float sw1[6][12], sb1[12], sw2[12][8], sb2[8];
    const int tid = threadIdx.x;
    if (tid < 72)        sw1[tid/12][tid%12] = w1[tid];
    else if (tid < 84)   sb1[tid-72] = b1[tid-72];
    else if (tid < 180)  sw2[(tid-84)/8][(tid-84)%8] = w2[tid-84];
    else if (tid < 188)  sb2[tid-180] = b2[tid-180];
    __syncthreads();

    const int b = blockIdx.y;
    const int ql = tid >> 7;
    const int qrow = blockIdx.x * 2 + ql;
    const int kk = (tid & 127) * 4;

    float xp[5][4];
    #pragma unroll
    for (int s = 0; s < 5; ++s) {
        float4 t = *(const float4*)&powers[((long)(s*Bz+b))*NNl + (long)qrow*Nn + kk];
        xp[s][0]=t.x; xp[s][1]=t.y; xp[s][2]=t.z; xp[s][3]=t.w;
    }
    float outh[8][4];
    #pragma unroll
    for (int j = 0; j < 4; ++j) {
        float hid[12];
        #pragma unroll
        for (int jj = 0; jj < 12; ++jj) {
            float v = sb1[jj];
            if (qrow == kk + j) v += sw1[0][jj];
            v = fmaf(xp[0][j], sw1[1][jj], v);
            v = fmaf(xp[1][j], sw1[2][jj], v);
            v = fmaf(xp[2][j], sw1[3][jj], v);
            v = fmaf(xp[3][j], sw1[4][jj], v);
            v = fmaf(xp[4][j], sw1[5][jj], v);
            hid[jj] = fmaxf(v, 0.f);
        }
        #pragma unroll
        for (int h = 0; h < 8; ++h) {
            float a = sb2[h];
            #pragma unroll
            for (int jj = 0; jj < 12; ++jj) a = fmaf(hid[jj], sw2[jj][h], a);
            outh[h][j] = a;
        }
    }
    #pragma unroll
    for (int h = 0; h < 8; ++h) {
        const long off = ((long)(b*Hh+h))*NNl + (long)qrow*Nn + kk;
        if (BF16OUT) {
            ushort4 u;
            u.x = f2bf(outh[h][0]); u.y = f2bf(outh[h][1]);
            u.z = f2bf(outh[h][2]); u.w = f2bf(outh[h][3]);
            *(ushort4*)((unsigned short*)biasOut + off) = u;
        } else {
            float4 o = {outh[h][0], outh[h][1], outh[h][2], outh[h][3]};
            *(float4*)((float*)biasOut + off) = o;
        }
    }
}

// ---------------------------------------------------------------------------
// Kernel 4: attention.
//   QK: 2q x 4k per thread (q-pair in regs), 128-key phases (2 tiles staged).
//       Thread's keys strided 16 (kg + 16j) -> scT writes 2-way only.
//   scT: flat [512 keys][20 floats] (16 q + 4 pad). Rows 16B-aligned:
//       QK writes float2, PV reads float4 (wave-uniform key, broadcast-free).
//   kvs swizzle kswz unchanged (proven round 4).
// ---------------------------------------------------------------------------
__device__ inline int kswz(int row, int slot) {
    return row * 68 + (((slot ^ ((row >> 2) & 7)) & 15) << 2);
}

template<bool BF16B>
__global__ __launch_bounds__(256, 2)
void attn2(const float* __restrict__ qkv, const void* __restrict__ biasT,
           const int* __restrict__ mask,
           float* __restrict__ ctx, float* __restrict__ wout)
{
    __shared__ float scTf[512 * 20];   // 40960 B
    __shared__ float kvs[2 * 4352];    // 34816 B (2 swizzled 64x64 tiles)

    const int qt = blockIdx.x, b = blockIdx.y;
    const int q0 = qt * 16;
    const int tid = threadIdx.x;

    // QK roles
    const int w     = tid >> 6;            // wave 0..3
    const int lane  = tid & 63;
    const int tsel  = w >> 1;              // tile within 128-key phase
    const int qbase = 8 * (w & 1) + 2 * (lane >> 4);  // first q row of pair
    const int kgq   = lane & 15;           // key group (stride-16 keys)
    // softmax roles
    const int qi = tid >> 4;               // q row 0..15
    const int kg = tid & 15;
    // PV roles
    const int kq = tid >> 6;
    const int qg = (tid >> 4) & 3;
    const int dg = tid & 15;

    float wacc[32];
    #pragma unroll
    for (int i = 0; i < 32; ++i) wacc[i] = 0.f;

    for (int h = 0; h < Hh; ++h) {
        // ---------------- pass 1: scores -> scT ----------------
        {
            float4 qA[16], qB[16];
            const float* qp0 = qkv + ((long)b*Nn + q0 + qbase)*(3*Dd) + h*HD;
            const float* qp1 = qp0 + 3*Dd;
            #pragma unroll
            for (int t = 0; t < 16; ++t) {
                qA[t] = *(const float4*)&qp0[t*4];
                qB[t] = *(const float4*)&qp1[t*4];
            }

            for (int p = 0; p < 4; ++p) {
                {   // stage 128 K rows into 2 tiles
                    const int row  = tid >> 1;
                    const int half = tid & 1;
                    const float* kp = qkv + ((long)b*Nn + p*128 + row)*(3*Dd)
                                      + Dd + h*HD + half*32;
                    float* base = &kvs[(row >> 6) * 4352];
                    const int rIT = row & 63;
                    #pragma unroll
                    for (int t = 0; t < 8; ++t)
                        *(float4*)&base[kswz(rIT, half*8 + t)] = *(const float4*)&kp[t*4];
                }
                __syncthreads();

                #pragma unroll
                for (int j = 0; j < 4; ++j) {
                    const int rowIT = kgq + 16*j;
                    const float* tb = &kvs[tsel * 4352];
                    float s0 = 0.f, s1 = 0.f;
                    #pragma unroll
                    for (int d4 = 0; d4 < 16; ++d4) {
                        float4 k4 = *(const float4*)&tb[kswz(rowIT, d4)];
                        s0 += qA[d4].x*k4.x + qA[d4].y*k4.y + qA[d4].z*k4.z + qA[d4].w*k4.w;
                        s1 += qB[d4].x*k4.x + qB[d4].y*k4.y + qB[d4].z*k4.z + qB[d4].w*k4.w;
                    }
                    const int gkey = p*128 + tsel*64 + rowIT;
                    float b0, b1;
                    if (BF16B) {
                        const unsigned short* bp = (const unsigned short*)biasT
                            + ((long)(b*Hh+h))*NNl + (long)(q0+qbase)*Nn + gkey;
                        b0 = bf2f(bp[0]); b1 = bf2f(bp[Nn]);
                    } else {
                        const float* bp = (const float*)biasT
                            + ((long)(b*Hh+h))*NNl + (long)(q0+qbase)*Nn + gkey;
                        b0 = bp[0]; b1 = bp[Nn];
                    }
                    const int mv = mask[(long)b*Nn + gkey];
                    float v0 = s0 * 0.125f + b0;
                    float v1 = s1 * 0.125f + b1;
                    if (!mv) { v0 = -1e9f; v1 = -1e9f; }
                    *(float2*)&scTf[gkey*20 + qbase] = make_float2(v0, v1);
                }
                __syncthreads();
            }
        }

        // ---------------- pass 2: softmax ----------------
        {
            float pv[32];
            float mx = -INFINITY;
            #pragma unroll
            for (int i = 0; i < 32; ++i) {
                pv[i] = scTf[(kg + 16*i)*20 + qi];
                mx = fmaxf(mx, pv[i]);
            }
            #pragma unroll
            for (int o = 1; o < 16; o <<= 1) mx = fmaxf(mx, __shfl_xor(mx, o));
            float sum = 0.f;
            #pragma unroll
            for (int i = 0; i < 32; ++i) { pv[i] = expf(pv[i] - mx); sum += pv[i]; }
            #pragma unroll
            for (int o = 1; o < 16; o <<= 1) sum += __shfl_xor(sum, o);
            const float inv = 1.f / sum;
            #pragma unroll
            for (int i = 0; i < 32; ++i) {
                const float p = pv[i] * inv;
                scTf[(kg + 16*i)*20 + qi] = p;
                wacc[i] += p;
            }
        }
        __syncthreads();

        // ---------------- pass 3: ctx = P @ V ----------------
        float4 acc[4];
        #pragma unroll
        for (int i = 0; i < 4; ++i) acc[i] = make_float4(0.f, 0.f, 0.f, 0.f);

        for (int p = 0; p < 4; ++p) {
            {   // stage 128 V rows
                const int row  = tid >> 1;
                const int half = tid & 1;
                const float* vp = qkv + ((long)b*Nn + p*128 + row)*(3*Dd)
                                  + 2*Dd + h*HD + half*32;
                float* base = &kvs[(row >> 6) * 4352];
                const int rIT = row & 63;
                #pragma unroll
                for (int t = 0; t < 8; ++t)
                    *(float4*)&base[kswz(rIT, half*8 + t)] = *(const float4*)&vp[t*4];
            }
            __syncthreads();

            #pragma unroll
            for (int tile = 0; tile < 2; ++tile) {
                const float* tb = &kvs[tile * 4352];
                const int kt = p*2 + tile;
                #pragma unroll
                for (int kk2 = 0; kk2 < 16; ++kk2) {
                    const int kl = kq*16 + kk2;
                    const int k  = kt*64 + kl;
                    float4 p4 = *(const float4*)&scTf[k*20 + qg*4];
                    float4 v4 = *(const float4*)&tb[kswz(kl, dg)];
                    acc[0].x = fmaf(p4.x, v4.x, acc[0].x); acc[0].y = fmaf(p4.x, v4.y, acc[0].y);
                    acc[0].z = fmaf(p4.x, v4.z, acc[0].z); acc[0].w = fmaf(p4.x, v4.w, acc[0].w);
                    acc[1].x = fmaf(p4.y, v4.x, acc[1].x); acc[1].y = fmaf(p4.y, v4.y, acc[1].y);
                    acc[1].z = fmaf(p4.y, v4.z, acc[1].z); acc[1].w = fmaf(p4.y, v4.w, acc[1].w);
                    acc[2].x = fmaf(p4.z, v4.x, acc[2].x); acc[2].y = fmaf(p4.z, v4.y, acc[2].y);
                    acc[2].z = fmaf(p4.z, v4.z, acc[2].z); acc[2].w = fmaf(p4.z, v4.w, acc[2].w);
                    acc[3].x = fmaf(p4.w, v4.x, acc[3].x); acc[3].y = fmaf(p4.w, v4.y, acc[3].y);
                    acc[3].z = fmaf(p4.w, v4.z, acc[3].z); acc[3].w = fmaf(p4.w, v4.w, acc[3].w);
                }
            }
            __syncthreads();
        }

        // k-split reduce via kvs scratch, stride-17 slots (2-way max)
        if (kq > 0) {
            float* dst = &kvs[0] + ((kq-1)*64 + (qg*16 + dg)) * 17;
            #pragma unroll
            for (int i = 0; i < 4; ++i) *(float4*)&dst[i*4] = acc[i];
        }
        __syncthreads();
        if (kq == 0) {
            #pragma unroll
            for (int k2 = 0; k2 < 3; ++k2) {
                const float* src = &kvs[0] + (k2*64 + (qg*16 + dg)) * 17;
                #pragma unroll
                for (int i = 0; i < 4; ++i) {
                    float4 t = *(const float4*)&src[i*4];
                    acc[i].x += t.x; acc[i].y += t.y; acc[i].z += t.z; acc[i].w += t.w;
                }
            }
            #pragma unroll
            for (int i = 0; i < 4; ++i)
                *(float4*)&ctx[((long)b*Nn + q0 + qg*4 + i)*Dd + h*HD + dg*4] = acc[i];
        }
        __syncthreads();
    }

    {
        float* wrow = wout + ((long)b*Nn + q0 + qi) * Nn;
        #pragma unroll
        for (int i = 0; i < 32; ++i) wrow[kg + 16*i] = wacc[i] * 0.125f;
    }
}

// ---------------------------------------------------------------------------
extern "C" void kernel_launch(void* const* d_in, const int* in_sizes, int n_in,
                              void* d_out, int out_size, void* d_ws, size_t ws_size,
                              hipStream_t stream)
{
    const float* h_in      = (const float*)d_in[0];
    const float* adj       = (const float*)d_in[1];
    const int*   mask      = (const int*)d_in[2];
    const float* in_proj_w = (const float*)d_in[3];
    const float* in_proj_b = (const float*)d_in[4];
    const float* out_w     = (const float*)d_in[5];
    const float* out_b     = (const float*)d_in[6];
    const float* ffn_w1    = (const float*)d_in[7];
    const float* ffn_b1    = (const float*)d_in[8];
    const float* ffn_w2    = (const float*)d_in[9];
    const float* ffn_b2    = (const float*)d_in[10];

    float* ws = (float*)d_ws;

    // Region layout (bytes):
    //   [0, 83886080)        : powers P^1..P^5 (5*BNN fp32) -- dead after bias_ffn
    //   [0, 50331648)        : qkv (overlays powers AFTER bias_ffn)
    //   [50331648, 67108864) : ctx
    //   [83886080, ...)      : bias fp32 (134 MB) or bf16 (67 MB)
    float* powers = ws;
    float* qkv    = ws;
    float* ctxb   = ws + 12582912;
    void*  biasT  = (void*)((char*)d_ws + 83886080);

    const bool fp32bias = (ws_size >= 218103808ull);

    float* out_atten = (float*)d_out;
    float* out_wts   = out_atten + BNNl;

    // P^1
    computeP<<<dim3(Nn, Bz), 64, 0, stream>>>(adj, mask, powers);

    // P^2..P^5
    for (int s = 1; s < 5; ++s) {
        gemm64<false, false><<<dim3(8, 4, Bz), 256, 0, stream>>>(
            powers + (long)(s-1)*BNNl, powers, nullptr, powers + (long)s*BNNl,
            Nn, Nn, Nn, NNl, NNl, NNl);
    }

    // edge-FFN bias
    if (fp32bias)
        bias_ffn<false><<<dim3(Nn/2, Bz), 256, 0, stream>>>(
            powers, ffn_w1, ffn_b1, ffn_w2, ffn_b2, biasT);
    else
        bias_ffn<true><<<dim3(Nn/2, Bz), 256, 0, stream>>>(
            powers, ffn_w1, ffn_b1, ffn_w2, ffn_b2, biasT);

    // qkv = h @ in_proj_w^T + b
    gemm128<true, true><<<dim3(12, 4, Bz), 256, 0, stream>>>(
        h_in, in_proj_w, in_proj_b, qkv,
        Nn, 3*Dd, Dd, (long)Nn*Dd, 0, (long)Nn*3*Dd);

    // attention
    if (fp32bias)
        attn2<false><<<dim3(Nn/16, Bz), 256, 0, stream>>>(qkv, biasT, mask, ctxb, out_wts);
    else
        attn2<true><<<dim3(Nn/16, Bz), 256, 0, stream>>>(qkv, biasT, mask, ctxb, out_wts);

    // atten_out = ctx @ out_w^T + out_b
    gemm64<true, true><<<dim3(8, 4, Bz), 256, 0, stream>>>(
        ctxb, out_w, out_b, out_atten,
        Nn, Dd, Dd, (long)Nn*Dd, 0, (long)Nn*Dd);
}